// Round 1
// baseline (219.826 us; speedup 1.0000x reference)
//
#include <hip/hip_runtime.h>
#include <hip/hip_bf16.h>
#include <math.h>

// Problem dims (fixed by the reference): B=4096, M=2, D=2048
#define MROWS 8192   // B*M rows of the GEMM
#define KDIM  2048
#define NDIM  2048

#define BM 128
#define BN 128
#define BK 64

typedef short  v8s __attribute__((ext_vector_type(8)));   // 8 bf16 (4 VGPRs)
typedef float  v4f __attribute__((ext_vector_type(4)));   // MFMA acc

// workspace layout (bytes)
#define A_OFF   0ull
#define W_OFF   ((unsigned long long)MROWS * KDIM * 2ull)               // 32 MiB
#define MWZ_OFF (W_OFF + (unsigned long long)NDIM * KDIM * 2ull)        // +8 MiB

__device__ inline unsigned short f2bf(float f) {
    __hip_bfloat16 h = __float2bfloat16(f);   // RNE
    return *reinterpret_cast<unsigned short*>(&h);
}

// ---------------------------------------------------------------------------
// Prep: zeta scalar, A = bf16(x + emb[ids]), W = bf16(Wt)
// ---------------------------------------------------------------------------
__global__ __launch_bounds__(256) void prep_kernel(
    const float* __restrict__ x, const int* __restrict__ ids,
    const float* __restrict__ mw, const float* __restrict__ emb,
    const float* __restrict__ Wrc, const float* __restrict__ brc,
    const float* __restrict__ Wt,
    unsigned short* __restrict__ Abf, unsigned short* __restrict__ Wbf,
    float* __restrict__ mwz)
{
    const int tid = threadIdx.x;

    // zeta = sigmoid(0.2 * sum(Wrc) + brc); block 0 only
    if (blockIdx.x == 0) {
        __shared__ float red[256];
        float s = 0.f;
        for (int d = tid; d < KDIM; d += 256) s += Wrc[d];
        red[tid] = s;
        __syncthreads();
        for (int off = 128; off > 0; off >>= 1) {
            if (tid < off) red[tid] += red[tid + off];
            __syncthreads();
        }
        if (tid == 0) {
            float zeta = 1.0f / (1.0f + expf(-(0.2f * red[0] + brc[0])));
            mwz[0] = mw[0] * zeta;
            mwz[1] = mw[1] * zeta;
        }
    }

    // A conversion: 8 floats -> 8 bf16 per thread-iter
    const int groupsA = MROWS * KDIM / 8;
    for (int g = blockIdx.x * 256 + tid; g < groupsA; g += gridDim.x * 256) {
        const int row = g >> 8;            // 256 groups of 8 per 2048-row
        const int off = (g & 255) << 3;
        const int st  = ids[row];
        const float4* xp = (const float4*)(x   + (size_t)row * KDIM + off);
        const float4* ep = (const float4*)(emb + (size_t)st  * KDIM + off);
        float4 x0 = xp[0], x1 = xp[1];
        float4 e0 = ep[0], e1 = ep[1];
        v8s o;
        o[0] = (short)f2bf(x0.x + e0.x);
        o[1] = (short)f2bf(x0.y + e0.y);
        o[2] = (short)f2bf(x0.z + e0.z);
        o[3] = (short)f2bf(x0.w + e0.w);
        o[4] = (short)f2bf(x1.x + e1.x);
        o[5] = (short)f2bf(x1.y + e1.y);
        o[6] = (short)f2bf(x1.z + e1.z);
        o[7] = (short)f2bf(x1.w + e1.w);
        *(v8s*)(Abf + (size_t)g * 8) = o;
    }

    // W conversion
    const int groupsW = NDIM * KDIM / 8;
    for (int g = blockIdx.x * 256 + tid; g < groupsW; g += gridDim.x * 256) {
        const float4* wp = (const float4*)(Wt + (size_t)g * 8);
        float4 w0 = wp[0], w1 = wp[1];
        v8s o;
        o[0] = (short)f2bf(w0.x); o[1] = (short)f2bf(w0.y);
        o[2] = (short)f2bf(w0.z); o[3] = (short)f2bf(w0.w);
        o[4] = (short)f2bf(w1.x); o[5] = (short)f2bf(w1.y);
        o[6] = (short)f2bf(w1.z); o[7] = (short)f2bf(w1.w);
        *(v8s*)(Wbf + (size_t)g * 8) = o;
    }
}

// ---------------------------------------------------------------------------
// GEMM: C[r][n] = sum_k A[r][k] * W[n][k]  (W stored row-major = B^T form)
// 128x128 block, 4 waves in 2x2, each wave 4x4 of 16x16x32 bf16 MFMA tiles.
// Epilogue: relu(mwz[r&1] * relu(acc + bt[n]))
// ---------------------------------------------------------------------------
__global__ __launch_bounds__(256) void gemm_kernel(
    const unsigned short* __restrict__ Abf,
    const unsigned short* __restrict__ Wbf,
    const float* __restrict__ bt,
    const float* __restrict__ mwz,
    float* __restrict__ out)
{
    __shared__ __align__(16) unsigned short lA[BM * BK];  // 16 KiB
    __shared__ __align__(16) unsigned short lB[BN * BK];  // 16 KiB

    const int tid  = threadIdx.x;
    const int lane = tid & 63;
    const int wave = tid >> 6;
    const int wr   = wave >> 1;       // wave row (0..1) -> 64 rows
    const int wc   = wave & 1;        // wave col (0..1) -> 64 cols
    const int quad = lane >> 4;       // 0..3
    const int mcol = lane & 15;       // 0..15

    const int br = blockIdx.x;        // 64 row-blocks
    const int bc = blockIdx.y;        // 16 col-blocks

    v4f acc[4][4];
    const v4f vzero = {0.f, 0.f, 0.f, 0.f};
    #pragma unroll
    for (int i = 0; i < 4; i++)
        #pragma unroll
        for (int j = 0; j < 4; j++) acc[i][j] = vzero;

    const unsigned short* gA = Abf + (size_t)(br * BM) * KDIM;
    const unsigned short* gB = Wbf + (size_t)(bc * BN) * KDIM;

    for (int kt = 0; kt < KDIM; kt += BK) {
        // ---- stage A and B tiles: 128 rows x 64 cols bf16 each = 16 KiB ----
        // LDS slot f holds row=f>>3, global chunk ch = (f&7) ^ (row&7)  (XOR
        // swizzle applied on the fetch side; LDS dest is forced base+lane*16)
        #pragma unroll
        for (int q = 0; q < 4; q++) {
            const int f   = q * 256 + tid;
            const int row = f >> 3;
            const int ch  = (f & 7) ^ (row & 7);
            const unsigned short* ga = gA + (size_t)row * KDIM + kt + ch * 8;
            const unsigned short* gb = gB + (size_t)row * KDIM + kt + ch * 8;
            __builtin_amdgcn_global_load_lds(
                (const __attribute__((address_space(1))) void*)ga,
                (__attribute__((address_space(3))) void*)(&lA[(size_t)f * 8]),
                16, 0, 0);
            __builtin_amdgcn_global_load_lds(
                (const __attribute__((address_space(1))) void*)gb,
                (__attribute__((address_space(3))) void*)(&lB[(size_t)f * 8]),
                16, 0, 0);
        }
        __syncthreads();   // drains vmcnt(0): staging complete

        // ---- compute: 2 k-steps of 16x16x32, 4x4 tiles per wave ----
        #pragma unroll
        for (int ks = 0; ks < BK; ks += 32) {
            v8s af[4], bf_[4];
            #pragma unroll
            for (int i = 0; i < 4; i++) {
                const int row = wr * 64 + i * 16 + mcol;       // A row (m)
                const int cc  = (ks >> 3) + quad;              // k-chunk
                const int c   = cc ^ (row & 7);                // unswizzle
                af[i] = *(const v8s*)(&lA[row * BK + c * 8]);
            }
            #pragma unroll
            for (int j = 0; j < 4; j++) {
                const int col = wc * 64 + j * 16 + mcol;       // B col (n)
                const int cc  = (ks >> 3) + quad;
                const int c   = cc ^ (col & 7);
                bf_[j] = *(const v8s*)(&lB[col * BK + c * 8]);
            }
            #pragma unroll
            for (int i = 0; i < 4; i++)
                #pragma unroll
                for (int j = 0; j < 4; j++)
                    acc[i][j] = __builtin_amdgcn_mfma_f32_16x16x32_bf16(
                        af[i], bf_[j], acc[i][j], 0, 0, 0);
        }
        __syncthreads();   // protect LDS before next stage overwrites
    }

    // ---- epilogue: bias + relu + scale + relu, fp32 store ----
    const float mz0 = mwz[0];
    const float mz1 = mwz[1];
    #pragma unroll
    for (int j = 0; j < 4; j++) {
        const int col  = bc * BN + wc * 64 + j * 16 + mcol;
        const float bias = bt[col];
        #pragma unroll
        for (int i = 0; i < 4; i++) {
            const int row0 = br * BM + wr * 64 + i * 16 + quad * 4;
            #pragma unroll
            for (int r = 0; r < 4; r++) {
                const int row = row0 + r;
                float t = acc[i][j][r] + bias;
                t = fmaxf(t, 0.0f);
                float h = ((row & 1) ? mz1 : mz0) * t;
                out[(size_t)row * NDIM + col] = fmaxf(h, 0.0f);
            }
        }
    }
}

// ---------------------------------------------------------------------------
extern "C" void kernel_launch(void* const* d_in, const int* in_sizes, int n_in,
                              void* d_out, int out_size, void* d_ws, size_t ws_size,
                              hipStream_t stream) {
    const float* x    = (const float*)d_in[0];
    const int*   ids  = (const int*)  d_in[1];
    const float* mw   = (const float*)d_in[2];
    const float* emb  = (const float*)d_in[3];
    const float* Wt   = (const float*)d_in[4];
    const float* bt   = (const float*)d_in[5];
    const float* Wrc  = (const float*)d_in[6];
    const float* brc  = (const float*)d_in[7];
    float* out = (float*)d_out;

    char* ws = (char*)d_ws;
    unsigned short* Abf = (unsigned short*)(ws + A_OFF);
    unsigned short* Wbf = (unsigned short*)(ws + W_OFF);
    float* mwz          = (float*)(ws + MWZ_OFF);

    prep_kernel<<<2048, 256, 0, stream>>>(x, ids, mw, emb, Wrc, brc, Wt,
                                          Abf, Wbf, mwz);

    dim3 grid(MROWS / BM, NDIM / BN);   // 64 x 16
    gemm_kernel<<<grid, 256, 0, stream>>>(Abf, Wbf, bt, mwz, out);
}

// Round 2
// 217.385 us; speedup vs baseline: 1.0112x; 1.0112x over previous
//
#include <hip/hip_runtime.h>
#include <hip/hip_bf16.h>
#include <math.h>

// Problem dims (fixed by the reference): B=4096, M=2, D=2048
#define MROWS 8192   // B*M rows of the GEMM
#define KDIM  2048
#define NDIM  2048

#define BM 128
#define BN 128
#define BK 64

typedef short  v8s __attribute__((ext_vector_type(8)));   // 8 bf16 (4 VGPRs)
typedef float  v4f __attribute__((ext_vector_type(4)));   // MFMA acc

// workspace layout (bytes)
#define A_OFF   0ull
#define W_OFF   ((unsigned long long)MROWS * KDIM * 2ull)               // 32 MiB
#define MWZ_OFF (W_OFF + (unsigned long long)NDIM * KDIM * 2ull)        // +8 MiB

__device__ inline unsigned short f2bf(float f) {
    __hip_bfloat16 h = __float2bfloat16(f);   // RNE
    return *reinterpret_cast<unsigned short*>(&h);
}

// ---------------------------------------------------------------------------
// Prep: zeta scalar, A = bf16(x + emb[ids]), W = bf16(Wt)
// ---------------------------------------------------------------------------
__global__ __launch_bounds__(256) void prep_kernel(
    const float* __restrict__ x, const int* __restrict__ ids,
    const float* __restrict__ mw, const float* __restrict__ emb,
    const float* __restrict__ Wrc, const float* __restrict__ brc,
    const float* __restrict__ Wt,
    unsigned short* __restrict__ Abf, unsigned short* __restrict__ Wbf,
    float* __restrict__ mwz)
{
    const int tid = threadIdx.x;

    // zeta = sigmoid(0.2 * sum(Wrc) + brc); block 0 only
    if (blockIdx.x == 0) {
        __shared__ float red[256];
        float s = 0.f;
        for (int d = tid; d < KDIM; d += 256) s += Wrc[d];
        red[tid] = s;
        __syncthreads();
        for (int off = 128; off > 0; off >>= 1) {
            if (tid < off) red[tid] += red[tid + off];
            __syncthreads();
        }
        if (tid == 0) {
            float zeta = 1.0f / (1.0f + expf(-(0.2f * red[0] + brc[0])));
            mwz[0] = mw[0] * zeta;
            mwz[1] = mw[1] * zeta;
        }
    }

    // A conversion: 8 floats -> 8 bf16 per thread-iter
    const int groupsA = MROWS * KDIM / 8;
    for (int g = blockIdx.x * 256 + tid; g < groupsA; g += gridDim.x * 256) {
        const int row = g >> 8;            // 256 groups of 8 per 2048-row
        const int off = (g & 255) << 3;
        const int st  = ids[row];
        const float4* xp = (const float4*)(x   + (size_t)row * KDIM + off);
        const float4* ep = (const float4*)(emb + (size_t)st  * KDIM + off);
        float4 x0 = xp[0], x1 = xp[1];
        float4 e0 = ep[0], e1 = ep[1];
        v8s o;
        o[0] = (short)f2bf(x0.x + e0.x);
        o[1] = (short)f2bf(x0.y + e0.y);
        o[2] = (short)f2bf(x0.z + e0.z);
        o[3] = (short)f2bf(x0.w + e0.w);
        o[4] = (short)f2bf(x1.x + e1.x);
        o[5] = (short)f2bf(x1.y + e1.y);
        o[6] = (short)f2bf(x1.z + e1.z);
        o[7] = (short)f2bf(x1.w + e1.w);
        *(v8s*)(Abf + (size_t)g * 8) = o;
    }

    // W conversion
    const int groupsW = NDIM * KDIM / 8;
    for (int g = blockIdx.x * 256 + tid; g < groupsW; g += gridDim.x * 256) {
        const float4* wp = (const float4*)(Wt + (size_t)g * 8);
        float4 w0 = wp[0], w1 = wp[1];
        v8s o;
        o[0] = (short)f2bf(w0.x); o[1] = (short)f2bf(w0.y);
        o[2] = (short)f2bf(w0.z); o[3] = (short)f2bf(w0.w);
        o[4] = (short)f2bf(w1.x); o[5] = (short)f2bf(w1.y);
        o[6] = (short)f2bf(w1.z); o[7] = (short)f2bf(w1.w);
        *(v8s*)(Wbf + (size_t)g * 8) = o;
    }
}

// ---------------------------------------------------------------------------
// GEMM: out[r][n] = sum_k A[r][k] * W[n][k]  (W stored row-major = B^T form)
// 128x128 block, 4 waves in 2x2, each wave 4x4 of 16x16x32 bf16 MFMA tiles.
// OPERAND SWAP: mfma(W_frag, A_frag) so acc holds out^T tiles — each lane's
// 4 acc regs are 4 CONSECUTIVE output columns at fixed row -> dwordx4 stores.
// Epilogue: relu(mwz[r&1] * relu(acc + bt[n]))
// ---------------------------------------------------------------------------
__global__ __launch_bounds__(256) void gemm_kernel(
    const unsigned short* __restrict__ Abf,
    const unsigned short* __restrict__ Wbf,
    const float* __restrict__ bt,
    const float* __restrict__ mwz,
    float* __restrict__ out)
{
    __shared__ __align__(16) unsigned short lA[BM * BK];  // 16 KiB
    __shared__ __align__(16) unsigned short lB[BN * BK];  // 16 KiB

    const int tid  = threadIdx.x;
    const int lane = tid & 63;
    const int wave = tid >> 6;
    const int wr   = wave >> 1;       // wave row (0..1) -> 64 rows
    const int wc   = wave & 1;        // wave col (0..1) -> 64 cols
    const int quad = lane >> 4;       // 0..3
    const int mcol = lane & 15;       // 0..15

    const int br = blockIdx.x;        // 64 row-blocks
    const int bc = blockIdx.y;        // 16 col-blocks

    v4f acc[4][4];
    const v4f vzero = {0.f, 0.f, 0.f, 0.f};
    #pragma unroll
    for (int i = 0; i < 4; i++)
        #pragma unroll
        for (int j = 0; j < 4; j++) acc[i][j] = vzero;

    const unsigned short* gA = Abf + (size_t)(br * BM) * KDIM;
    const unsigned short* gB = Wbf + (size_t)(bc * BN) * KDIM;

    for (int kt = 0; kt < KDIM; kt += BK) {
        // ---- stage A and B tiles: 128 rows x 64 cols bf16 each = 16 KiB ----
        // LDS slot f holds row=f>>3, global chunk ch = (f&7) ^ (row&7)  (XOR
        // swizzle applied on the fetch side; LDS dest is forced base+lane*16)
        #pragma unroll
        for (int q = 0; q < 4; q++) {
            const int f   = q * 256 + tid;
            const int row = f >> 3;
            const int ch  = (f & 7) ^ (row & 7);
            const unsigned short* ga = gA + (size_t)row * KDIM + kt + ch * 8;
            const unsigned short* gb = gB + (size_t)row * KDIM + kt + ch * 8;
            __builtin_amdgcn_global_load_lds(
                (const __attribute__((address_space(1))) void*)ga,
                (__attribute__((address_space(3))) void*)(&lA[(size_t)f * 8]),
                16, 0, 0);
            __builtin_amdgcn_global_load_lds(
                (const __attribute__((address_space(1))) void*)gb,
                (__attribute__((address_space(3))) void*)(&lB[(size_t)f * 8]),
                16, 0, 0);
        }
        __syncthreads();   // drains vmcnt(0): staging complete

        // ---- compute: 2 k-steps of 16x16x32, 4x4 tiles per wave ----
        #pragma unroll
        for (int ks = 0; ks < BK; ks += 32) {
            v8s af[4], bf_[4];
            #pragma unroll
            for (int i = 0; i < 4; i++) {
                const int row = wr * 64 + i * 16 + mcol;       // A row (m)
                const int cc  = (ks >> 3) + quad;              // k-chunk
                const int c   = cc ^ (row & 7);                // unswizzle
                af[i] = *(const v8s*)(&lA[row * BK + c * 8]);
            }
            #pragma unroll
            for (int j = 0; j < 4; j++) {
                const int col = wc * 64 + j * 16 + mcol;       // B col (n)
                const int cc  = (ks >> 3) + quad;
                const int c   = cc ^ (col & 7);
                bf_[j] = *(const v8s*)(&lB[col * BK + c * 8]);
            }
            // operand swap: D = W_frag x A_frag  => acc[i][j] is out^T tile:
            //   r-index (quad*4+reg) = output COLUMN, c-index (mcol) = output ROW
            #pragma unroll
            for (int i = 0; i < 4; i++)
                #pragma unroll
                for (int j = 0; j < 4; j++)
                    acc[i][j] = __builtin_amdgcn_mfma_f32_16x16x32_bf16(
                        bf_[j], af[i], acc[i][j], 0, 0, 0);
        }
        __syncthreads();   // protect LDS before next stage overwrites
    }

    // ---- epilogue: bias + relu + scale + relu, dwordx4 fp32 stores ----
    // row parity: all tile offsets even, so parity = mcol & 1
    const float mz = mwz[mcol & 1];
    #pragma unroll
    for (int j = 0; j < 4; j++) {
        const int ncol = bc * BN + wc * 64 + j * 16 + quad * 4;  // 4 consecutive cols
        const float4 b4 = *(const float4*)(bt + ncol);
        #pragma unroll
        for (int i = 0; i < 4; i++) {
            const int row = br * BM + wr * 64 + i * 16 + mcol;
            float4 o;
            o.x = fmaxf(mz * fmaxf(acc[i][j][0] + b4.x, 0.0f), 0.0f);
            o.y = fmaxf(mz * fmaxf(acc[i][j][1] + b4.y, 0.0f), 0.0f);
            o.z = fmaxf(mz * fmaxf(acc[i][j][2] + b4.z, 0.0f), 0.0f);
            o.w = fmaxf(mz * fmaxf(acc[i][j][3] + b4.w, 0.0f), 0.0f);
            *(float4*)(out + (size_t)row * NDIM + ncol) = o;
        }
    }
}

// ---------------------------------------------------------------------------
extern "C" void kernel_launch(void* const* d_in, const int* in_sizes, int n_in,
                              void* d_out, int out_size, void* d_ws, size_t ws_size,
                              hipStream_t stream) {
    const float* x    = (const float*)d_in[0];
    const int*   ids  = (const int*)  d_in[1];
    const float* mw   = (const float*)d_in[2];
    const float* emb  = (const float*)d_in[3];
    const float* Wt   = (const float*)d_in[4];
    const float* bt   = (const float*)d_in[5];
    const float* Wrc  = (const float*)d_in[6];
    const float* brc  = (const float*)d_in[7];
    float* out = (float*)d_out;

    char* ws = (char*)d_ws;
    unsigned short* Abf = (unsigned short*)(ws + A_OFF);
    unsigned short* Wbf = (unsigned short*)(ws + W_OFF);
    float* mwz          = (float*)(ws + MWZ_OFF);

    prep_kernel<<<2048, 256, 0, stream>>>(x, ids, mw, emb, Wrc, brc, Wt,
                                          Abf, Wbf, mwz);

    dim3 grid(MROWS / BM, NDIM / BN);   // 64 x 16
    gemm_kernel<<<grid, 256, 0, stream>>>(Abf, Wbf, bt, mwz, out);
}

// Round 3
// 201.970 us; speedup vs baseline: 1.0884x; 1.0763x over previous
//
#include <hip/hip_runtime.h>
#include <hip/hip_bf16.h>
#include <math.h>

// Problem dims (fixed by the reference): B=4096, M=2, D=2048
#define MROWS 8192   // B*M rows of the GEMM
#define KDIM  2048
#define NDIM  2048

#define BM 256
#define BN 128
#define BK 64

typedef short  v8s __attribute__((ext_vector_type(8)));   // 8 bf16 (4 VGPRs)
typedef float  v4f __attribute__((ext_vector_type(4)));   // MFMA acc

// workspace layout (bytes)
#define A_OFF   0ull
#define W_OFF   ((unsigned long long)MROWS * KDIM * 2ull)               // 32 MiB
#define MWZ_OFF (W_OFF + (unsigned long long)NDIM * KDIM * 2ull)        // +8 MiB

__device__ inline unsigned short f2bf(float f) {
    __hip_bfloat16 h = __float2bfloat16(f);   // RNE
    return *reinterpret_cast<unsigned short*>(&h);
}

// ---------------------------------------------------------------------------
// Prep: zeta scalar, A = bf16(x + emb[ids]), W = bf16(Wt)
// ---------------------------------------------------------------------------
__global__ __launch_bounds__(256) void prep_kernel(
    const float* __restrict__ x, const int* __restrict__ ids,
    const float* __restrict__ mw, const float* __restrict__ emb,
    const float* __restrict__ Wrc, const float* __restrict__ brc,
    const float* __restrict__ Wt,
    unsigned short* __restrict__ Abf, unsigned short* __restrict__ Wbf,
    float* __restrict__ mwz)
{
    const int tid = threadIdx.x;

    // zeta = sigmoid(0.2 * sum(Wrc) + brc); block 0 only
    if (blockIdx.x == 0) {
        __shared__ float red[256];
        float s = 0.f;
        for (int d = tid; d < KDIM; d += 256) s += Wrc[d];
        red[tid] = s;
        __syncthreads();
        for (int off = 128; off > 0; off >>= 1) {
            if (tid < off) red[tid] += red[tid + off];
            __syncthreads();
        }
        if (tid == 0) {
            float zeta = 1.0f / (1.0f + expf(-(0.2f * red[0] + brc[0])));
            mwz[0] = mw[0] * zeta;
            mwz[1] = mw[1] * zeta;
        }
    }

    // A conversion: 8 floats -> 8 bf16 per thread-iter
    const int groupsA = MROWS * KDIM / 8;
    for (int g = blockIdx.x * 256 + tid; g < groupsA; g += gridDim.x * 256) {
        const int row = g >> 8;            // 256 groups of 8 per 2048-row
        const int off = (g & 255) << 3;
        const int st  = ids[row];
        const float4* xp = (const float4*)(x   + (size_t)row * KDIM + off);
        const float4* ep = (const float4*)(emb + (size_t)st  * KDIM + off);
        float4 x0 = xp[0], x1 = xp[1];
        float4 e0 = ep[0], e1 = ep[1];
        v8s o;
        o[0] = (short)f2bf(x0.x + e0.x);
        o[1] = (short)f2bf(x0.y + e0.y);
        o[2] = (short)f2bf(x0.z + e0.z);
        o[3] = (short)f2bf(x0.w + e0.w);
        o[4] = (short)f2bf(x1.x + e1.x);
        o[5] = (short)f2bf(x1.y + e1.y);
        o[6] = (short)f2bf(x1.z + e1.z);
        o[7] = (short)f2bf(x1.w + e1.w);
        *(v8s*)(Abf + (size_t)g * 8) = o;
    }

    // W conversion
    const int groupsW = NDIM * KDIM / 8;
    for (int g = blockIdx.x * 256 + tid; g < groupsW; g += gridDim.x * 256) {
        const float4* wp = (const float4*)(Wt + (size_t)g * 8);
        float4 w0 = wp[0], w1 = wp[1];
        v8s o;
        o[0] = (short)f2bf(w0.x); o[1] = (short)f2bf(w0.y);
        o[2] = (short)f2bf(w0.z); o[3] = (short)f2bf(w0.w);
        o[4] = (short)f2bf(w1.x); o[5] = (short)f2bf(w1.y);
        o[6] = (short)f2bf(w1.z); o[7] = (short)f2bf(w1.w);
        *(v8s*)(Wbf + (size_t)g * 8) = o;
    }
}

// ---------------------------------------------------------------------------
// GEMM: out[r][n] = sum_k A[r][k] * W[n][k]  (W stored row-major = B^T form)
// 256x128 block, 4 waves in 2(M)x2(N); each wave owns a 128x64 tile =
// 8x4 of 16x16x32 bf16 MFMA. 512 blocks = exactly 2/CU x 256 CU -> no tail.
// OPERAND SWAP: mfma(W_frag, A_frag) -> acc holds out^T; lane's 4 acc regs
// are 4 consecutive output columns at fixed row -> dwordx4 stores.
// Epilogue: relu(mwz[row&1] * relu(acc + bt[n]))
// ---------------------------------------------------------------------------
__global__ __launch_bounds__(256, 2) void gemm_kernel(
    const unsigned short* __restrict__ Abf,
    const unsigned short* __restrict__ Wbf,
    const float* __restrict__ bt,
    const float* __restrict__ mwz,
    float* __restrict__ out)
{
    __shared__ __align__(16) unsigned short lA[BM * BK];  // 32 KiB
    __shared__ __align__(16) unsigned short lB[BN * BK];  // 16 KiB

    const int tid  = threadIdx.x;
    const int lane = tid & 63;
    const int wave = tid >> 6;
    const int wr   = wave & 1;        // wave M-half (0..1) -> 128 rows
    const int wc   = wave >> 1;       // wave N-half (0..1) -> 64 cols
    const int quad = lane >> 4;       // 0..3
    const int mcol = lane & 15;       // 0..15

    const int br = blockIdx.x;        // 32 row-blocks
    const int bc = blockIdx.y;        // 16 col-blocks

    v4f acc[8][4];
    const v4f vzero = {0.f, 0.f, 0.f, 0.f};
    #pragma unroll
    for (int i = 0; i < 8; i++)
        #pragma unroll
        for (int j = 0; j < 4; j++) acc[i][j] = vzero;

    const unsigned short* gA = Abf + (size_t)(br * BM) * KDIM;
    const unsigned short* gB = Wbf + (size_t)(bc * BN) * KDIM;

    for (int kt = 0; kt < KDIM; kt += BK) {
        // ---- stage A (256x64) and B (128x64) bf16 tiles: 48 KiB ----
        // LDS slot f holds row=f>>3, global chunk ch = (f&7) ^ (row&7)  (XOR
        // swizzle applied on the fetch side; LDS dest is forced base+lane*16)
        #pragma unroll
        for (int q = 0; q < 8; q++) {
            const int f   = q * 256 + tid;
            const int row = f >> 3;
            const int ch  = (f & 7) ^ (row & 7);
            const unsigned short* ga = gA + (size_t)row * KDIM + kt + ch * 8;
            __builtin_amdgcn_global_load_lds(
                (const __attribute__((address_space(1))) void*)ga,
                (__attribute__((address_space(3))) void*)(&lA[(size_t)f * 8]),
                16, 0, 0);
        }
        #pragma unroll
        for (int q = 0; q < 4; q++) {
            const int f   = q * 256 + tid;
            const int row = f >> 3;
            const int ch  = (f & 7) ^ (row & 7);
            const unsigned short* gb = gB + (size_t)row * KDIM + kt + ch * 8;
            __builtin_amdgcn_global_load_lds(
                (const __attribute__((address_space(1))) void*)gb,
                (__attribute__((address_space(3))) void*)(&lB[(size_t)f * 8]),
                16, 0, 0);
        }
        __syncthreads();   // drains vmcnt(0): staging complete

        // ---- compute: 2 k-steps of 16x16x32, 8x4 tiles per wave ----
        #pragma unroll
        for (int ks = 0; ks < BK; ks += 32) {
            v8s af[8], bf_[4];
            #pragma unroll
            for (int i = 0; i < 8; i++) {
                const int row = wr * 128 + i * 16 + mcol;      // A row (m)
                const int cc  = (ks >> 3) + quad;              // k-chunk
                const int c   = cc ^ (row & 7);                // unswizzle
                af[i] = *(const v8s*)(&lA[row * BK + c * 8]);
            }
            #pragma unroll
            for (int j = 0; j < 4; j++) {
                const int col = wc * 64 + j * 16 + mcol;       // B col (n)
                const int cc  = (ks >> 3) + quad;
                const int c   = cc ^ (col & 7);
                bf_[j] = *(const v8s*)(&lB[col * BK + c * 8]);
            }
            // operand swap: D = W_frag x A_frag  => acc[i][j] is out^T tile:
            //   reg-index (quad*4+r) = output COLUMN, mcol = output ROW
            #pragma unroll
            for (int i = 0; i < 8; i++)
                #pragma unroll
                for (int j = 0; j < 4; j++)
                    acc[i][j] = __builtin_amdgcn_mfma_f32_16x16x32_bf16(
                        bf_[j], af[i], acc[i][j], 0, 0, 0);
        }
        __syncthreads();   // protect LDS before next stage overwrites
    }

    // ---- epilogue: bias + relu + scale + relu, dwordx4 fp32 stores ----
    // row parity: all tile offsets even, so parity = mcol & 1
    const float mz = mwz[mcol & 1];
    #pragma unroll
    for (int j = 0; j < 4; j++) {
        const int ncol = bc * BN + wc * 64 + j * 16 + quad * 4;  // 4 consecutive cols
        const float4 b4 = *(const float4*)(bt + ncol);
        #pragma unroll
        for (int i = 0; i < 8; i++) {
            const int row = br * BM + wr * 128 + i * 16 + mcol;
            float4 o;
            o.x = fmaxf(mz * fmaxf(acc[i][j][0] + b4.x, 0.0f), 0.0f);
            o.y = fmaxf(mz * fmaxf(acc[i][j][1] + b4.y, 0.0f), 0.0f);
            o.z = fmaxf(mz * fmaxf(acc[i][j][2] + b4.z, 0.0f), 0.0f);
            o.w = fmaxf(mz * fmaxf(acc[i][j][3] + b4.w, 0.0f), 0.0f);
            *(float4*)(out + (size_t)row * NDIM + ncol) = o;
        }
    }
}

// ---------------------------------------------------------------------------
extern "C" void kernel_launch(void* const* d_in, const int* in_sizes, int n_in,
                              void* d_out, int out_size, void* d_ws, size_t ws_size,
                              hipStream_t stream) {
    const float* x    = (const float*)d_in[0];
    const int*   ids  = (const int*)  d_in[1];
    const float* mw   = (const float*)d_in[2];
    const float* emb  = (const float*)d_in[3];
    const float* Wt   = (const float*)d_in[4];
    const float* bt   = (const float*)d_in[5];
    const float* Wrc  = (const float*)d_in[6];
    const float* brc  = (const float*)d_in[7];
    float* out = (float*)d_out;

    char* ws = (char*)d_ws;
    unsigned short* Abf = (unsigned short*)(ws + A_OFF);
    unsigned short* Wbf = (unsigned short*)(ws + W_OFF);
    float* mwz          = (float*)(ws + MWZ_OFF);

    prep_kernel<<<2048, 256, 0, stream>>>(x, ids, mw, emb, Wrc, brc, Wt,
                                          Abf, Wbf, mwz);

    dim3 grid(MROWS / BM, NDIM / BN);   // 32 x 16 = 512 blocks = 2/CU exactly
    gemm_kernel<<<grid, 256, 0, stream>>>(Abf, Wbf, bt, mwz, out);
}